// Round 3
// baseline (53.576 us; speedup 1.0000x reference)
//
#include <hip/hip_runtime.h>
#include <math.h>

#define LOG2E 1.4426950408889634f

// consts layout (7 floats):
//   [0]    softmax coeff of the min-exponent term (its exp factor == 1)
//   [1..3] softmax coeffs of the other 3 terms
//   [4..6] (e2_k - e2_min) / |a|   (log2-domain exponent deltas, pre-divided)

// ---------------------------------------------------------------------------
// Kernel 1: per-atom table (z, z^|a_exp|), zero output, scalar consts.
// ---------------------------------------------------------------------------
__global__ __launch_bounds__(256) void zbl_prep_kernel(
    const float* __restrict__ z, const float* __restrict__ a_coef,
    const float* __restrict__ a_exp, const float* __restrict__ phi_c,
    const float* __restrict__ phi_e, float2* __restrict__ tab,
    float* __restrict__ out, float* __restrict__ consts, int n_atoms) {
  int n = blockIdx.x * blockDim.x + threadIdx.x;
  if (n < n_atoms) {
    float zi = z[n];                       // in [1, 94] -> log2 safe
    float ae = fabsf(a_exp[0]);
    float za = __builtin_amdgcn_exp2f(ae * __builtin_amdgcn_logf(zi));
    tab[n] = make_float2(zi, za);
    out[n] = 0.0f;
  }
  if (blockIdx.x == 0 && threadIdx.x == 0) {
    float c[4], e2[4];
    float m = -1e30f;
    for (int k = 0; k < 4; ++k) { c[k] = fabsf(phi_c[k]); m = fmaxf(m, c[k]); }
    float s = 0.0f;
    for (int k = 0; k < 4; ++k) { c[k] = expf(c[k] - m); s += c[k]; }
    for (int k = 0; k < 4; ++k) c[k] /= s;
    int kmin = 0;
    for (int k = 0; k < 4; ++k) {
      e2[k] = fabsf(phi_e[k]) * LOG2E;
      if (e2[k] < e2[kmin]) kmin = k;
    }
    float inv_a = 1.0f / fabsf(a_coef[0]);
    consts[0] = c[kmin];
    int p = 1;
    for (int k = 0; k < 4; ++k) {
      if (k != kmin) {
        consts[p] = c[k];
        consts[3 + p] = (e2[k] - e2[kmin]) * inv_a;
        ++p;
      }
    }
  }
}

// ---------------------------------------------------------------------------
// Kernel 2: each wave handles 256 consecutive edges as 4 chunks of 64
// (1 edge/lane per chunk). Per chunk: fast-math edge value, then the
// R1-verified wave-segmented suffix reduce + run-head atomic emission
// (atom_mask folded in). Correct for any key layout; cheap because idx_i
// is sorted (~2 runs per 64-edge chunk -> ~200k atomics total).
// ---------------------------------------------------------------------------
__global__ __launch_bounds__(256) void zbl_edge_kernel(
    const float* __restrict__ disp, const int* __restrict__ idx_i,
    const int* __restrict__ idx_j, const float* __restrict__ bmask,
    const float2* __restrict__ tab, const float* __restrict__ consts,
    const float* __restrict__ amask, float* __restrict__ out, int n_edges) {
  const int lane = threadIdx.x & 63;
  const long wave = (long)blockIdx.x * (blockDim.x >> 6) + (threadIdx.x >> 6);
  const long base = wave * 256;

  const float c0 = consts[0], c1 = consts[1], c2 = consts[2], c3 = consts[3];
  const float dd1 = consts[4], dd2 = consts[5], dd3 = consts[6];

  #pragma unroll
  for (int c = 0; c < 4; ++c) {
    const long e = base + (long)(c << 6) + lane;
    int key = -1;
    float v = 0.0f;
    if (e < (long)n_edges) {
      const int i = idx_i[e];
      const int j = idx_j[e];
      const float dx = disp[3 * e + 0];
      const float dy = disp[3 * e + 1];
      const float dz = disp[3 * e + 2];
      float n2 = fmaxf(dx * dx + dy * dy + dz * dz, 1e-20f);
      float r = __builtin_amdgcn_rsqf(n2);  // 1/d
      float d = n2 * r;                     // d = sqrt(n2)
      // smooth switch on [CUTON=4, CUTOFF=5]
      float x = 5.0f - d;
      float poly = ((6.0f * x - 15.0f) * x + 10.0f) * x * x * x;
      float sw = (d < 4.0f) ? 1.0f : ((d >= 5.0f) ? 0.0f : poly);
      float2 ti = tab[i];
      float2 tj = tab[j];
      float q = d * fmaxf(ti.y + tj.y, 1e-10f);
      // phi = c_min + sum_k c_k * 2^(-dd_k * q)   (== reference's shifted-exp
      // quirk: max_log = -e_min*arg is always the max since arg >= 0)
      float phi = c0 + c1 * __builtin_amdgcn_exp2f(-dd1 * q)
                     + c2 * __builtin_amdgcn_exp2f(-dd2 * q)
                     + c3 * __builtin_amdgcn_exp2f(-dd3 * q);
      v = 0.5f * ti.x * tj.x * r * fmaxf(phi, 1e-30f) *
          fmaxf(sw, 1e-30f) * bmask[e];
      key = i;
    }

    // R1-verified wave-segmented suffix sum over equal adjacent keys.
    #pragma unroll
    for (int off = 1; off < 64; off <<= 1) {
      float v2 = __shfl_down(v, off, 64);
      int k2 = __shfl_down(key, off, 64);
      if (lane + off < 64 && k2 == key) v += v2;
    }
    int kup = __shfl_up(key, 1, 64);
    if (key >= 0 && (lane == 0 || kup != key))
      atomicAdd(&out[key], v * amask[key]);
  }
}

extern "C" void kernel_launch(void* const* d_in, const int* in_sizes, int n_in,
                              void* d_out, int out_size, void* d_ws,
                              size_t ws_size, hipStream_t stream) {
  const float* atomic_numbers = (const float*)d_in[0];
  const float* disp           = (const float*)d_in[1];
  const int*   idx_i          = (const int*)d_in[2];
  const int*   idx_j          = (const int*)d_in[3];
  const float* atom_mask      = (const float*)d_in[4];
  // d_in[5] = batch_segments (unused), d_in[7] = batch_size (unused)
  const float* bmask          = (const float*)d_in[6];
  const float* a_coef         = (const float*)d_in[8];
  const float* a_exp          = (const float*)d_in[9];
  const float* phi_c          = (const float*)d_in[10];
  const float* phi_e          = (const float*)d_in[11];

  int n_atoms = in_sizes[0];
  int n_edges = in_sizes[2];

  float* out = (float*)d_out;
  float2* tab = (float2*)d_ws;
  float* consts = (float*)((char*)d_ws + (size_t)n_atoms * sizeof(float2));

  int atom_blocks = (n_atoms + 255) / 256;
  long waves = ((long)n_edges + 255) / 256;       // 256 edges per wave
  int edge_blocks = (int)((waves + 3) / 4);       // 4 waves per block

  zbl_prep_kernel<<<atom_blocks, 256, 0, stream>>>(
      atomic_numbers, a_coef, a_exp, phi_c, phi_e, tab, out, consts, n_atoms);
  zbl_edge_kernel<<<edge_blocks, 256, 0, stream>>>(
      disp, idx_i, idx_j, bmask, tab, consts, atom_mask, out, n_edges);
}

// Round 4
// 47.395 us; speedup vs baseline: 1.1304x; 1.1304x over previous
//
#include <hip/hip_runtime.h>
#include <math.h>

#define LOG2E 1.4426950408889634f
#define NSLOT 512   // LDS accumulator slots per block (block spans ~16 atoms)
#define EPB   1024  // edges per block (256 threads x 4 edges)

// consts layout (7 floats):
//   [0]    softmax coeff of the min-exponent term (its exp factor == 1)
//   [1..3] softmax coeffs of the other 3 terms
//   [4..6] (e2_k - e2_min) / |a|   (log2-domain exponent deltas, pre-divided)

// ---------------------------------------------------------------------------
// Kernel 1: per-atom table (z, z^|a_exp|), zero output, scalar consts.
// ---------------------------------------------------------------------------
__global__ __launch_bounds__(256) void zbl_prep_kernel(
    const float* __restrict__ z, const float* __restrict__ a_coef,
    const float* __restrict__ a_exp, const float* __restrict__ phi_c,
    const float* __restrict__ phi_e, float2* __restrict__ tab,
    float* __restrict__ out, float* __restrict__ consts, int n_atoms) {
  int n = blockIdx.x * blockDim.x + threadIdx.x;
  if (n < n_atoms) {
    float zi = z[n];                       // in [1, 94] -> log safe
    float ae = fabsf(a_exp[0]);
    float za = __builtin_amdgcn_exp2f(ae * __builtin_amdgcn_logf(zi));
    tab[n] = make_float2(zi, za);
    out[n] = 0.0f;
  }
  if (blockIdx.x == 0 && threadIdx.x == 0) {
    float c[4], e2[4];
    float m = -1e30f;
    for (int k = 0; k < 4; ++k) { c[k] = fabsf(phi_c[k]); m = fmaxf(m, c[k]); }
    float s = 0.0f;
    for (int k = 0; k < 4; ++k) { c[k] = expf(c[k] - m); s += c[k]; }
    for (int k = 0; k < 4; ++k) c[k] /= s;
    int kmin = 0;
    for (int k = 0; k < 4; ++k) {
      e2[k] = fabsf(phi_e[k]) * LOG2E;
      if (e2[k] < e2[kmin]) kmin = k;
    }
    float inv_a = 1.0f / fabsf(a_coef[0]);
    consts[0] = c[kmin];
    int p = 1;
    for (int k = 0; k < 4; ++k) {
      if (k != kmin) {
        consts[p] = c[k];
        consts[3 + p] = (e2[k] - e2[kmin]) * inv_a;
        ++p;
      }
    }
  }
}

// ---------------------------------------------------------------------------
// Per-edge math (verified in R3): rep value + segment key.
// ---------------------------------------------------------------------------
__device__ __forceinline__ void zbl_edge_compute(
    float dx, float dy, float dz, int i, int j, float bm,
    const float2* __restrict__ tab, float c0, float c1, float c2, float c3,
    float dd1, float dd2, float dd3, int& kk, float& vv) {
  float n2 = fmaxf(dx * dx + dy * dy + dz * dz, 1e-20f);
  float r = __builtin_amdgcn_rsqf(n2);  // 1/d
  float d = n2 * r;                     // d = sqrt(n2)
  // smooth switch on [CUTON=4, CUTOFF=5]
  float x = 5.0f - d;
  float poly = ((6.0f * x - 15.0f) * x + 10.0f) * x * x * x;
  float sw = (d < 4.0f) ? 1.0f : ((d >= 5.0f) ? 0.0f : poly);
  float2 ti = tab[i];
  float2 tj = tab[j];
  float q = d * fmaxf(ti.y + tj.y, 1e-10f);
  // phi = c_min + sum_k c_k * 2^(-dd_k*q)  (reference's shifted-exp quirk:
  // max_log = -e_min*arg is always the max term since arg >= 0)
  float phi = c0 + c1 * __builtin_amdgcn_exp2f(-dd1 * q)
                 + c2 * __builtin_amdgcn_exp2f(-dd2 * q)
                 + c3 * __builtin_amdgcn_exp2f(-dd3 * q);
  vv = 0.5f * ti.x * tj.x * r * fmaxf(phi, 1e-30f) * fmaxf(sw, 1e-30f) * bm;
  kk = i;
}

// ---------------------------------------------------------------------------
// Kernel 2: block owns 1024 consecutive edges (4/thread, vectorized loads).
// In-register run merge -> LDS float atomics into slots keyed relative to the
// block's first atom (sorted idx_i => span ~16 atoms) -> barrier -> sweep
// slots, one global atomic per touched atom with atom_mask folded in.
// Out-of-range keys (unsorted/pathological) fall back to global atomics, so
// correctness never depends on sortedness.
// ---------------------------------------------------------------------------
__global__ __launch_bounds__(256) void zbl_edge_kernel(
    const float* __restrict__ disp, const int* __restrict__ idx_i,
    const int* __restrict__ idx_j, const float* __restrict__ bmask,
    const float2* __restrict__ tab, const float* __restrict__ consts,
    const float* __restrict__ amask, float* __restrict__ out, int n_edges) {
  __shared__ float acc[NSLOT];
  const int t = threadIdx.x;
  const long block_base = (long)blockIdx.x * EPB;

  acc[t] = 0.0f;
  acc[t + 256] = 0.0f;

  const int key_base = idx_i[block_base];  // uniform broadcast load
  const float c0 = consts[0], c1 = consts[1], c2 = consts[2], c3 = consts[3];
  const float dd1 = consts[4], dd2 = consts[5], dd3 = consts[6];

  const long L = (long)blockIdx.x * 256 + t;  // global quad id
  const long e0 = L * 4;

  int k[4] = {-1, -1, -1, -1};
  float v[4] = {0.f, 0.f, 0.f, 0.f};

  if (e0 + 3 < (long)n_edges) {
    const float4* d4 = (const float4*)disp;
    float4 A = d4[3 * L], B = d4[3 * L + 1], Cc = d4[3 * L + 2];
    int4 I = ((const int4*)idx_i)[L];
    int4 J = ((const int4*)idx_j)[L];
    float4 BM = ((const float4*)bmask)[L];
    // disp unpack: e0=(A.x,A.y,A.z) e1=(A.w,B.x,B.y) e2=(B.z,B.w,Cc.x)
    //              e3=(Cc.y,Cc.z,Cc.w)
    zbl_edge_compute(A.x, A.y, A.z, I.x, J.x, BM.x, tab, c0, c1, c2, c3, dd1, dd2, dd3, k[0], v[0]);
    zbl_edge_compute(A.w, B.x, B.y, I.y, J.y, BM.y, tab, c0, c1, c2, c3, dd1, dd2, dd3, k[1], v[1]);
    zbl_edge_compute(B.z, B.w, Cc.x, I.z, J.z, BM.z, tab, c0, c1, c2, c3, dd1, dd2, dd3, k[2], v[2]);
    zbl_edge_compute(Cc.y, Cc.z, Cc.w, I.w, J.w, BM.w, tab, c0, c1, c2, c3, dd1, dd2, dd3, k[3], v[3]);
  } else {
    #pragma unroll
    for (int m = 0; m < 4; ++m) {
      const long e = e0 + m;
      if (e < (long)n_edges)
        zbl_edge_compute(disp[3 * e], disp[3 * e + 1], disp[3 * e + 2],
                         idx_i[e], idx_j[e], bmask[e], tab, c0, c1, c2, c3,
                         dd1, dd2, dd3, k[m], v[m]);
    }
  }

  __syncthreads();  // LDS zeroing complete before any atomics land

  auto flush = [&](int key, float s) {
    if (key < 0) return;
    int slot = key - key_base;
    if ((unsigned)slot < (unsigned)NSLOT) atomicAdd(&acc[slot], s);
    else atomicAdd(&out[key], s * amask[key]);
  };

  // in-register merge of equal-adjacent keys (sorted => ~1 run per thread)
  int cur = k[0];
  float s = v[0];
  #pragma unroll
  for (int m = 1; m < 4; ++m) {
    if (k[m] == cur) {
      s += v[m];
    } else {
      flush(cur, s);
      cur = k[m];
      s = v[m];
    }
  }
  flush(cur, s);

  __syncthreads();  // all LDS accumulation done

  #pragma unroll
  for (int s2 = 0; s2 < NSLOT; s2 += 256) {
    float val = acc[t + s2];
    if (val != 0.0f) {  // zero-valued slots contribute nothing; skip is exact
      int a = key_base + t + s2;
      atomicAdd(&out[a], val * amask[a]);
    }
  }
}

extern "C" void kernel_launch(void* const* d_in, const int* in_sizes, int n_in,
                              void* d_out, int out_size, void* d_ws,
                              size_t ws_size, hipStream_t stream) {
  const float* atomic_numbers = (const float*)d_in[0];
  const float* disp           = (const float*)d_in[1];
  const int*   idx_i          = (const int*)d_in[2];
  const int*   idx_j          = (const int*)d_in[3];
  const float* atom_mask      = (const float*)d_in[4];
  // d_in[5] = batch_segments (unused), d_in[7] = batch_size (unused)
  const float* bmask          = (const float*)d_in[6];
  const float* a_coef         = (const float*)d_in[8];
  const float* a_exp          = (const float*)d_in[9];
  const float* phi_c          = (const float*)d_in[10];
  const float* phi_e          = (const float*)d_in[11];

  int n_atoms = in_sizes[0];
  int n_edges = in_sizes[2];

  float* out = (float*)d_out;
  float2* tab = (float2*)d_ws;
  float* consts = (float*)((char*)d_ws + (size_t)n_atoms * sizeof(float2));

  int atom_blocks = (n_atoms + 255) / 256;
  int edge_blocks = (int)(((long)n_edges + EPB - 1) / EPB);

  zbl_prep_kernel<<<atom_blocks, 256, 0, stream>>>(
      atomic_numbers, a_coef, a_exp, phi_c, phi_e, tab, out, consts, n_atoms);
  zbl_edge_kernel<<<edge_blocks, 256, 0, stream>>>(
      disp, idx_i, idx_j, bmask, tab, consts, atom_mask, out, n_edges);
}